// Round 14
// baseline (135.863 us; speedup 1.0000x reference)
//
#include <hip/hip_runtime.h>
#include <hip/hip_fp16.h>

#define N_NODES 50000
#define N_EDGES 800000
#define IN_F    512
#define HID_F   128
#define OUT_F   16
#define CAP     64                   // bucket slots per node (Poisson(16): P(deg>64) ~ 1e-20)

typedef __attribute__((ext_vector_type(8))) short short8v;
typedef __attribute__((ext_vector_type(4))) float float4v;
typedef unsigned int uint32;
typedef unsigned short ushort16;

typedef __attribute__((address_space(3))) void lds_vp;
typedef __attribute__((address_space(1))) const void g_vp;

__device__ __forceinline__ ushort16 f2bf(float f) {
    uint32 u = __float_as_uint(f);
    uint32 r = (u + 0x7FFFu + ((u >> 16) & 1u)) >> 16;   // RNE
    return (ushort16)r;
}
__device__ __forceinline__ float bf_lo(uint32 h) { return __uint_as_float(h << 16); }
__device__ __forceinline__ float bf_hi(uint32 h) { return __uint_as_float(h & 0xFFFF0000u); }
__device__ __forceinline__ uint32 pack2bf(float a, float b) {
    return (uint32)f2bf(a) | ((uint32)f2bf(b) << 16);
}
__device__ __forceinline__ float pk_val(uint32 u) {
    return __half2float(__ushort_as_half((unsigned short)(u >> 16)));
}

// ---------------- fused prep: W1 transpose->bf16 + cursor zero ----------------
__global__ __launch_bounds__(256) void prep(const float* __restrict__ W1,
                                            unsigned short* __restrict__ W1T,
                                            int* __restrict__ cursor) {
    const int idx = blockIdx.x * 256 + threadIdx.x;
    if (idx < IN_F * HID_F) {
        const int k = idx >> 7;      // 0..511
        const int c = idx & 127;     // 0..127
        W1T[(size_t)c * IN_F + k] = (unsigned short)f2bf(W1[idx]);
    }
    if (idx < N_NODES) cursor[idx] = 0;
}

// ---------------- one-pass bucketed CSR fill ----------------
__global__ __launch_bounds__(256) void fill_bucket(const int* __restrict__ src,
                                                   const int* __restrict__ dst,
                                                   const float* __restrict__ val,
                                                   int* __restrict__ cursor,
                                                   uint32* __restrict__ bucket) {
    const int e = blockIdx.x * 256 + threadIdx.x;
    if (e >= N_EDGES) return;
    const int d = dst[e];
    const int s = src[e];
    const float v = val[e];
    const int p = atomicAdd(&cursor[d], 1);
    const unsigned short hb = __half_as_ushort(__float2half_rn(v));
    const uint32 pk = (uint32)s | ((uint32)hb << 16);
    if (p < CAP) bucket[(size_t)d * CAP + p] = pk;
}

// ---------------- GEMM1 (global_load_lds staged, double-buffered) -----------
// BM=64, BN=128, BK=64, 2-phase pipeline: stage(t+1) overlaps compute(t),
// ONE barrier per K-tile. Swizzled global source, linear DMA dest (T2/m173).
__global__ __launch_bounds__(256) void gemm1_lds(const float* __restrict__ X,
                                                 const short* __restrict__ W1T,
                                                 ushort16* __restrict__ H0) {
    __shared__ float4  Xs[2][1024];    // 2 x 16 KB: granule idx = r*16 + slot
    __shared__ short8v Ws[2][1024];    // 2 x 16 KB: granule idx = col*8 + slot
    const int t    = threadIdx.x;
    const int lane = t & 63;
    const int w    = t >> 6;
    const int l15  = lane & 15;
    const int kg   = (lane >> 4) * 8;     // lane k-slice within a 32-k step
    const int bm   = blockIdx.x * 64;

    float4v acc[8];
#pragma unroll
    for (int n = 0; n < 8; ++n) acc[n] = (float4v){0.f, 0.f, 0.f, 0.f};

    const int ra = w * 16 + l15;          // A-row this lane reads fragments for

    // staging addresses (loop-invariant pieces)
    const int xr   = t >> 2;              // X granule row this thread stages (with i*64 offset)
    const int xs   = t & 3;               // ...
    // stage one K-tile into buffer b
    auto stage = [&](int b, int k0) {
#pragma unroll
        for (int i = 0; i < 4; ++i) {
            const int idx = i * 256 + t;          // granule 0..1023
            const int r   = idx >> 4;             // 0..63
            const int s   = idx & 15;             // lds slot in row
            const int c4  = s ^ (r & 15);         // swizzled global granule
            const int grow = min(bm + r, N_NODES - 1);
            const float* g = X + (size_t)grow * IN_F + k0 + c4 * 4;
            __builtin_amdgcn_global_load_lds((g_vp*)g, (lds_vp*)&Xs[b][idx], 16, 0, 0);
        }
#pragma unroll
        for (int i = 0; i < 4; ++i) {
            const int idx = i * 256 + t;          // granule 0..1023
            const int col = idx >> 3;             // 0..127
            const int s   = idx & 7;              // lds slot in col
            const int gsl = s ^ (col & 7);        // swizzled global granule
            const short* g = W1T + (size_t)col * IN_F + k0 + gsl * 8;
            __builtin_amdgcn_global_load_lds((g_vp*)g, (lds_vp*)&Ws[b][idx], 16, 0, 0);
        }
    };

    stage(0, 0);
    __syncthreads();                      // drains vmcnt: tile 0 ready

#pragma unroll
    for (int kt = 0; kt < 8; ++kt) {
        const int cur = kt & 1;
        if (kt < 7) stage(cur ^ 1, (kt + 1) * 64);   // DMA overlaps compute below
#pragma unroll
        for (int ks = 0; ks < 64; ks += 32) {
            const int j0 = (ks + kg) >> 2;        // first fp32 granule of A slice
            const float4 a0 = Xs[cur][ra * 16 + ((j0)     ^ (ra & 15))];
            const float4 a1 = Xs[cur][ra * 16 + ((j0 + 1) ^ (ra & 15))];
            short8v af;
            af[0] = (short)f2bf(a0.x); af[1] = (short)f2bf(a0.y);
            af[2] = (short)f2bf(a0.z); af[3] = (short)f2bf(a0.w);
            af[4] = (short)f2bf(a1.x); af[5] = (short)f2bf(a1.y);
            af[6] = (short)f2bf(a1.z); af[7] = (short)f2bf(a1.w);
            const int gb = (ks + kg) >> 3;        // bf16 granule of B slice
#pragma unroll
            for (int n = 0; n < 8; ++n) {
                const int col = n * 16 + l15;
                const short8v bf = Ws[cur][col * 8 + (gb ^ (col & 7))];
                acc[n] = __builtin_amdgcn_mfma_f32_16x16x32_bf16(af, bf, acc[n], 0, 0, 0);
            }
        }
        __syncthreads();   // waits DMA(t+1) done + all waves done reading cur
    }

    // C/D layout: col = lane&15, row = (lane>>4)*4 + reg   [m89-verified]
    const int crow0 = bm + w * 16 + (lane >> 4) * 4;
#pragma unroll
    for (int rr = 0; rr < 4; ++rr) {
        const int grow = crow0 + rr;
        if (grow < N_NODES) {
#pragma unroll
            for (int n = 0; n < 8; ++n)
                H0[(size_t)grow * HID_F + n * 16 + l15] = f2bf(acc[n][rr]);
        }
    }
}

// ---------------- SpMM1 (bucket gather, 16/8-deep pipeline) + ReLU ----------
__global__ __launch_bounds__(256) void spmm1_bucket(const uint32* __restrict__ H0u,
                                                    const int* __restrict__ cursor,
                                                    const uint32* __restrict__ bucket,
                                                    uint32* __restrict__ S1) {
    const int r    = blockIdx.x * 4 + (threadIdx.x >> 6);
    const int lane = threadIdx.x & 63;
    if (r >= N_NODES) return;
    const int cnt = min(cursor[r], CAP);
    const uint32 pk = bucket[(size_t)r * CAP + lane];   // coalesced, full row edge list
    float a0 = 0.f, a1 = 0.f;
    int j = 0;
    for (; j + 16 <= cnt; j += 16) {
        uint32 uu[16], hh[16];
#pragma unroll
        for (int q = 0; q < 16; ++q) {
            uu[q] = __shfl(pk, j + q);
            hh[q] = H0u[(size_t)(uu[q] & 0xFFFF) * 64 + lane];
        }
#pragma unroll
        for (int q = 0; q < 16; ++q) {
            const float v = pk_val(uu[q]);
            a0 += v * bf_lo(hh[q]);
            a1 += v * bf_hi(hh[q]);
        }
    }
    for (; j + 8 <= cnt; j += 8) {
        uint32 uu[8], hh[8];
#pragma unroll
        for (int q = 0; q < 8; ++q) {
            uu[q] = __shfl(pk, j + q);
            hh[q] = H0u[(size_t)(uu[q] & 0xFFFF) * 64 + lane];
        }
#pragma unroll
        for (int q = 0; q < 8; ++q) {
            const float v = pk_val(uu[q]);
            a0 += v * bf_lo(hh[q]);
            a1 += v * bf_hi(hh[q]);
        }
    }
    for (; j < cnt; ++j) {
        const uint32 u = __shfl(pk, j);
        const uint32 h = H0u[(size_t)(u & 0xFFFF) * 64 + lane];
        const float v  = pk_val(u);
        a0 += v * bf_lo(h);
        a1 += v * bf_hi(h);
    }
    S1[(size_t)r * 64 + lane] = pack2bf(fmaxf(a0, 0.f), fmaxf(a1, 0.f));
}

// ---------------- GEMM2: H2 = S1 @ W2   (S1 bf16, out fp32) ----------------
__global__ __launch_bounds__(256) void gemm2(const uint32* __restrict__ S1,
                                             const float* __restrict__ W2,
                                             float* __restrict__ H2) {
    __shared__ float w[HID_F * OUT_F];
    const int t = threadIdx.x;
#pragma unroll
    for (int i = 0; i < 8; ++i) w[t + i * 256] = W2[t + i * 256];
    __syncthreads();
    const int c    = t & 15;
    const int rloc = t >> 4;
    const int r    = blockIdx.x * 16 + rloc;
    if (r >= N_NODES) return;
    const uint32* row = S1 + (size_t)r * 64;
    float acc = 0.f;
#pragma unroll 8
    for (int k2 = 0; k2 < 64; ++k2) {
        const uint32 h = row[k2];
        acc += bf_lo(h) * w[(2 * k2) * OUT_F + c];
        acc += bf_hi(h) * w[(2 * k2 + 1) * OUT_F + c];
    }
    H2[(size_t)r * OUT_F + c] = acc;
}

// ---------------- SpMM2 (bucket gather, 8-deep pipeline) + log_softmax ------
__global__ __launch_bounds__(256) void spmm2_ls(const float* __restrict__ H2,
                                                const int* __restrict__ cursor,
                                                const uint32* __restrict__ bucket,
                                                float* __restrict__ out) {
    const int r = blockIdx.x * 16 + (threadIdx.x >> 4);
    const int f = threadIdx.x & 15;
    if (r >= N_NODES) return;
    const int cnt = min(cursor[r], CAP);
    float acc = 0.f;
    for (int base = 0; base < cnt; base += 16) {
        const uint32 pk = bucket[(size_t)r * CAP + base + f];
        const int lim = min(16, cnt - base);
        int j = 0;
        for (; j + 8 <= lim; j += 8) {
            uint32 uu[8];
            float  hh[8];
#pragma unroll
            for (int q = 0; q < 8; ++q) {
                uu[q] = __shfl(pk, j + q, 16);
                hh[q] = H2[(size_t)(uu[q] & 0xFFFF) * OUT_F + f];
            }
#pragma unroll
            for (int q = 0; q < 8; ++q) acc += pk_val(uu[q]) * hh[q];
        }
        for (; j < lim; ++j) {
            const uint32 u = __shfl(pk, j, 16);
            acc += pk_val(u) * H2[(size_t)(u & 0xFFFF) * OUT_F + f];
        }
    }
    float m = acc;
#pragma unroll
    for (int off = 1; off < 16; off <<= 1) m = fmaxf(m, __shfl_xor(m, off, 16));
    const float ex = __expf(acc - m);
    float ss = ex;
#pragma unroll
    for (int off = 1; off < 16; off <<= 1) ss += __shfl_xor(ss, off, 16);
    out[(size_t)r * OUT_F + f] = acc - m - logf(ss);
}

extern "C" void kernel_launch(void* const* d_in, const int* in_sizes, int n_in,
                              void* d_out, int out_size, void* d_ws, size_t ws_size,
                              hipStream_t stream) {
    const float* x        = (const float*)d_in[0];
    const int*   edge_src = (const int*)d_in[1];
    const int*   edge_dst = (const int*)d_in[2];
    const float* edge_val = (const float*)d_in[3];
    const float* W1       = (const float*)d_in[4];
    const float* W2       = (const float*)d_in[5];
    float* out = (float*)d_out;

    char* ws = (char*)d_ws;
    size_t off = 0;
    ushort16* H0  = (ushort16*)(ws + off); off += (size_t)N_NODES * HID_F * 2;   // 12.8 MB bf16
    uint32* S1    = (uint32*)  (ws + off); off += (size_t)N_NODES * HID_F * 2;   // 12.8 MB bf16
    uint32* bucket= (uint32*)  (ws + off); off += (size_t)N_NODES * CAP * 4;     // 12.8 MB
    int*   cursor = (int*)     (ws + off); off += (size_t)N_NODES * 4;           // 0.2 MB
    unsigned short* W1T = (unsigned short*)(ws + off); off += (size_t)IN_F * HID_F * 2; // 128 KB
    float* H2 = (float*)H0;   // H0 dead after spmm1; reuse 3.2 MB

    // --- fused prep: W1 transpose->bf16 + cursor zero; then bucket fill ---
    prep<<<(IN_F * HID_F + 255) / 256, 256, 0, stream>>>(W1, W1T, cursor);
    fill_bucket<<<(N_EDGES + 255) / 256, 256, 0, stream>>>(edge_src, edge_dst, edge_val,
                                                           cursor, bucket);

    // --- H0 = bf16(x @ W1) ---
    gemm1_lds<<<(N_NODES + 63) / 64, 256, 0, stream>>>(x, (const short*)W1T, H0);

    // --- S1 = bf16(relu(A @ H0)) ---
    spmm1_bucket<<<(N_NODES + 3) / 4, 256, 0, stream>>>((const uint32*)H0, cursor, bucket, S1);

    // --- H2 = S1 @ W2 (fp32 out) ---
    gemm2<<<(N_NODES + 15) / 16, 256, 0, stream>>>(S1, W2, H2);

    // --- out = log_softmax(A @ H2) ---
    spmm2_ls<<<(N_NODES + 15) / 16, 256, 0, stream>>>(H2, cursor, bucket, out);
}

// Round 15
// 116.789 us; speedup vs baseline: 1.1633x; 1.1633x over previous
//
#include <hip/hip_runtime.h>
#include <hip/hip_fp16.h>

#define N_NODES 50000
#define N_EDGES 800000
#define IN_F    512
#define HID_F   128
#define OUT_F   16
#define CAP     64                   // bucket slots per node (Poisson(16): P(deg>64) ~ 1e-20)
#define FILL_BLOCKS 3125             // N_EDGES / 256
#define GEMM_BLOCKS 782              // ceil(N_NODES / 64)

typedef __attribute__((ext_vector_type(8))) short short8v;
typedef __attribute__((ext_vector_type(4))) float float4v;
typedef unsigned int uint32;
typedef unsigned short ushort16;

typedef __attribute__((address_space(3))) void lds_vp;
typedef __attribute__((address_space(1))) const void g_vp;

__device__ __forceinline__ ushort16 f2bf(float f) {
    uint32 u = __float_as_uint(f);
    uint32 r = (u + 0x7FFFu + ((u >> 16) & 1u)) >> 16;   // RNE
    return (ushort16)r;
}
__device__ __forceinline__ float bf_lo(uint32 h) { return __uint_as_float(h << 16); }
__device__ __forceinline__ float bf_hi(uint32 h) { return __uint_as_float(h & 0xFFFF0000u); }
__device__ __forceinline__ uint32 pack2bf(float a, float b) {
    return (uint32)f2bf(a) | ((uint32)f2bf(b) << 16);
}
__device__ __forceinline__ float pk_val(uint32 u) {
    return __half2float(__ushort_as_half((unsigned short)(u >> 16)));
}

// ---------------- fused prep: W1 transpose->bf16 + cursor zero ----------------
__global__ __launch_bounds__(256) void prep(const float* __restrict__ W1,
                                            unsigned short* __restrict__ W1T,
                                            int* __restrict__ cursor) {
    const int idx = blockIdx.x * 256 + threadIdx.x;
    if (idx < IN_F * HID_F) {
        const int k = idx >> 7;      // 0..511
        const int c = idx & 127;     // 0..127
        W1T[(size_t)c * IN_F + k] = (unsigned short)f2bf(W1[idx]);
    }
    if (idx < N_NODES) cursor[idx] = 0;
}

// ---------------- FAT kernel: fill_bucket ∥ gemm1 (independent work) --------
// Every 5th block runs one gemm1 64-row tile; the rest run 256-edge fill chunks.
// Both populations co-reside per CU: scatter latency hides under MFMA compute.
__global__ __launch_bounds__(256) void fill_and_gemm1(
        const int* __restrict__ src, const int* __restrict__ dst,
        const float* __restrict__ val, int* __restrict__ cursor,
        uint32* __restrict__ bucket,
        const float* __restrict__ X, const short* __restrict__ W1T,
        ushort16* __restrict__ H0) {
    if ((blockIdx.x % 5) != 0) {
        // ---------------- fill role ----------------
        const int fb = blockIdx.x - blockIdx.x / 5 - 1;
        if (fb >= FILL_BLOCKS) return;
        const int e = fb * 256 + threadIdx.x;
        if (e >= N_EDGES) return;
        const int d = dst[e];
        const int s = src[e];
        const float v = val[e];
        const int p = atomicAdd(&cursor[d], 1);
        const unsigned short hb = __half_as_ushort(__float2half_rn(v));
        const uint32 pk = (uint32)s | ((uint32)hb << 16);
        if (p < CAP) bucket[(size_t)d * CAP + p] = pk;
        return;
    }
    // ---------------- gemm1 role (single-buffer LDS, r12-proven) ----------------
    __shared__ float4  Xs[1024];    // 16 KB: granule idx = r*16 + slot
    __shared__ short8v Ws[1024];    // 16 KB: granule idx = col*8 + slot
    const int gb_id = blockIdx.x / 5;
    const int t    = threadIdx.x;
    const int lane = t & 63;
    const int w    = t >> 6;
    const int l15  = lane & 15;
    const int kg   = (lane >> 4) * 8;     // lane k-slice within a 32-k step
    const int bm   = gb_id * 64;

    float4v acc[8];
#pragma unroll
    for (int n = 0; n < 8; ++n) acc[n] = (float4v){0.f, 0.f, 0.f, 0.f};

    const int ra = w * 16 + l15;          // A-row this lane reads fragments for

    for (int k0 = 0; k0 < IN_F; k0 += 64) {
#pragma unroll
        for (int i = 0; i < 4; ++i) {
            const int idx = i * 256 + t;          // granule 0..1023
            const int r   = idx >> 4;             // 0..63
            const int s   = idx & 15;             // lds slot in row
            const int c4  = s ^ (r & 15);         // swizzled global granule
            const int grow = min(bm + r, N_NODES - 1);
            const float* g = X + (size_t)grow * IN_F + k0 + c4 * 4;
            __builtin_amdgcn_global_load_lds((g_vp*)g, (lds_vp*)&Xs[idx], 16, 0, 0);
        }
#pragma unroll
        for (int i = 0; i < 4; ++i) {
            const int idx = i * 256 + t;          // granule 0..1023
            const int col = idx >> 3;             // 0..127
            const int s   = idx & 7;              // lds slot in col
            const int gsl = s ^ (col & 7);        // swizzled global granule
            const short* g = W1T + (size_t)col * IN_F + k0 + gsl * 8;
            __builtin_amdgcn_global_load_lds((g_vp*)g, (lds_vp*)&Ws[idx], 16, 0, 0);
        }
        __syncthreads();
#pragma unroll
        for (int ks = 0; ks < 64; ks += 32) {
            const int j0 = (ks + kg) >> 2;        // first fp32 granule of A slice
            const float4 a0 = Xs[ra * 16 + ((j0)     ^ (ra & 15))];
            const float4 a1 = Xs[ra * 16 + ((j0 + 1) ^ (ra & 15))];
            short8v af;
            af[0] = (short)f2bf(a0.x); af[1] = (short)f2bf(a0.y);
            af[2] = (short)f2bf(a0.z); af[3] = (short)f2bf(a0.w);
            af[4] = (short)f2bf(a1.x); af[5] = (short)f2bf(a1.y);
            af[6] = (short)f2bf(a1.z); af[7] = (short)f2bf(a1.w);
            const int gbn = (ks + kg) >> 3;       // bf16 granule of B slice
#pragma unroll
            for (int n = 0; n < 8; ++n) {
                const int col = n * 16 + l15;
                const short8v bf = Ws[col * 8 + (gbn ^ (col & 7))];
                acc[n] = __builtin_amdgcn_mfma_f32_16x16x32_bf16(af, bf, acc[n], 0, 0, 0);
            }
        }
        __syncthreads();
    }

    // C/D layout: col = lane&15, row = (lane>>4)*4 + reg   [m89-verified]
    const int crow0 = bm + w * 16 + (lane >> 4) * 4;
#pragma unroll
    for (int rr = 0; rr < 4; ++rr) {
        const int grow = crow0 + rr;
        if (grow < N_NODES) {
#pragma unroll
            for (int n = 0; n < 8; ++n)
                H0[(size_t)grow * HID_F + n * 16 + l15] = f2bf(acc[n][rr]);
        }
    }
}

// ---------------- SpMM1 (bucket gather, 16/8-deep pipeline) + ReLU ----------
__global__ __launch_bounds__(256) void spmm1_bucket(const uint32* __restrict__ H0u,
                                                    const int* __restrict__ cursor,
                                                    const uint32* __restrict__ bucket,
                                                    uint32* __restrict__ S1) {
    const int r    = blockIdx.x * 4 + (threadIdx.x >> 6);
    const int lane = threadIdx.x & 63;
    if (r >= N_NODES) return;
    const int cnt = min(cursor[r], CAP);
    const uint32 pk = bucket[(size_t)r * CAP + lane];   // coalesced, full row edge list
    float a0 = 0.f, a1 = 0.f;
    int j = 0;
    for (; j + 16 <= cnt; j += 16) {
        uint32 uu[16], hh[16];
#pragma unroll
        for (int q = 0; q < 16; ++q) {
            uu[q] = __shfl(pk, j + q);
            hh[q] = H0u[(size_t)(uu[q] & 0xFFFF) * 64 + lane];
        }
#pragma unroll
        for (int q = 0; q < 16; ++q) {
            const float v = pk_val(uu[q]);
            a0 += v * bf_lo(hh[q]);
            a1 += v * bf_hi(hh[q]);
        }
    }
    for (; j + 8 <= cnt; j += 8) {
        uint32 uu[8], hh[8];
#pragma unroll
        for (int q = 0; q < 8; ++q) {
            uu[q] = __shfl(pk, j + q);
            hh[q] = H0u[(size_t)(uu[q] & 0xFFFF) * 64 + lane];
        }
#pragma unroll
        for (int q = 0; q < 8; ++q) {
            const float v = pk_val(uu[q]);
            a0 += v * bf_lo(hh[q]);
            a1 += v * bf_hi(hh[q]);
        }
    }
    for (; j < cnt; ++j) {
        const uint32 u = __shfl(pk, j);
        const uint32 h = H0u[(size_t)(u & 0xFFFF) * 64 + lane];
        const float v  = pk_val(u);
        a0 += v * bf_lo(h);
        a1 += v * bf_hi(h);
    }
    S1[(size_t)r * 64 + lane] = pack2bf(fmaxf(a0, 0.f), fmaxf(a1, 0.f));
}

// ---------------- GEMM2: H2 = S1 @ W2   (S1 bf16, out fp32) ----------------
__global__ __launch_bounds__(256) void gemm2(const uint32* __restrict__ S1,
                                             const float* __restrict__ W2,
                                             float* __restrict__ H2) {
    __shared__ float w[HID_F * OUT_F];
    const int t = threadIdx.x;
#pragma unroll
    for (int i = 0; i < 8; ++i) w[t + i * 256] = W2[t + i * 256];
    __syncthreads();
    const int c    = t & 15;
    const int rloc = t >> 4;
    const int r    = blockIdx.x * 16 + rloc;
    if (r >= N_NODES) return;
    const uint32* row = S1 + (size_t)r * 64;
    float acc = 0.f;
#pragma unroll 8
    for (int k2 = 0; k2 < 64; ++k2) {
        const uint32 h = row[k2];
        acc += bf_lo(h) * w[(2 * k2) * OUT_F + c];
        acc += bf_hi(h) * w[(2 * k2 + 1) * OUT_F + c];
    }
    H2[(size_t)r * OUT_F + c] = acc;
}

// ---------------- SpMM2 (bucket gather, 8-deep pipeline) + log_softmax ------
__global__ __launch_bounds__(256) void spmm2_ls(const float* __restrict__ H2,
                                                const int* __restrict__ cursor,
                                                const uint32* __restrict__ bucket,
                                                float* __restrict__ out) {
    const int r = blockIdx.x * 16 + (threadIdx.x >> 4);
    const int f = threadIdx.x & 15;
    if (r >= N_NODES) return;
    const int cnt = min(cursor[r], CAP);
    float acc = 0.f;
    for (int base = 0; base < cnt; base += 16) {
        const uint32 pk = bucket[(size_t)r * CAP + base + f];
        const int lim = min(16, cnt - base);
        int j = 0;
        for (; j + 8 <= lim; j += 8) {
            uint32 uu[8];
            float  hh[8];
#pragma unroll
            for (int q = 0; q < 8; ++q) {
                uu[q] = __shfl(pk, j + q, 16);
                hh[q] = H2[(size_t)(uu[q] & 0xFFFF) * OUT_F + f];
            }
#pragma unroll
            for (int q = 0; q < 8; ++q) acc += pk_val(uu[q]) * hh[q];
        }
        for (; j < lim; ++j) {
            const uint32 u = __shfl(pk, j, 16);
            acc += pk_val(u) * H2[(size_t)(u & 0xFFFF) * OUT_F + f];
        }
    }
    float m = acc;
#pragma unroll
    for (int off = 1; off < 16; off <<= 1) m = fmaxf(m, __shfl_xor(m, off, 16));
    const float ex = __expf(acc - m);
    float ss = ex;
#pragma unroll
    for (int off = 1; off < 16; off <<= 1) ss += __shfl_xor(ss, off, 16);
    out[(size_t)r * OUT_F + f] = acc - m - logf(ss);
}

extern "C" void kernel_launch(void* const* d_in, const int* in_sizes, int n_in,
                              void* d_out, int out_size, void* d_ws, size_t ws_size,
                              hipStream_t stream) {
    const float* x        = (const float*)d_in[0];
    const int*   edge_src = (const int*)d_in[1];
    const int*   edge_dst = (const int*)d_in[2];
    const float* edge_val = (const float*)d_in[3];
    const float* W1       = (const float*)d_in[4];
    const float* W2       = (const float*)d_in[5];
    float* out = (float*)d_out;

    char* ws = (char*)d_ws;
    size_t off = 0;
    ushort16* H0  = (ushort16*)(ws + off); off += (size_t)N_NODES * HID_F * 2;   // 12.8 MB bf16
    uint32* S1    = (uint32*)  (ws + off); off += (size_t)N_NODES * HID_F * 2;   // 12.8 MB bf16
    uint32* bucket= (uint32*)  (ws + off); off += (size_t)N_NODES * CAP * 4;     // 12.8 MB
    int*   cursor = (int*)     (ws + off); off += (size_t)N_NODES * 4;           // 0.2 MB
    unsigned short* W1T = (unsigned short*)(ws + off); off += (size_t)IN_F * HID_F * 2; // 128 KB
    float* H2 = (float*)H0;   // H0 dead after spmm1; reuse 3.2 MB

    // --- fused prep: W1 transpose->bf16 + cursor zero ---
    prep<<<(IN_F * HID_F + 255) / 256, 256, 0, stream>>>(W1, W1T, cursor);

    // --- fill_bucket ∥ gemm1 in one fat launch (independent work overlaps) ---
    fill_and_gemm1<<<GEMM_BLOCKS * 5, 256, 0, stream>>>(edge_src, edge_dst, edge_val,
                                                        cursor, bucket,
                                                        x, (const short*)W1T, H0);

    // --- S1 = bf16(relu(A @ H0)) ---
    spmm1_bucket<<<(N_NODES + 3) / 4, 256, 0, stream>>>((const uint32*)H0, cursor, bucket, S1);

    // --- H2 = S1 @ W2 (fp32 out) ---
    gemm2<<<(N_NODES + 15) / 16, 256, 0, stream>>>(S1, W2, H2);

    // --- out = log_softmax(A @ H2) ---
    spmm2_ls<<<(N_NODES + 15) / 16, 256, 0, stream>>>(H2, cursor, bucket, out);
}